// Round 8
// baseline (97.986 us; speedup 1.0000x reference)
//
#include <hip/hip_runtime.h>
#include <hip/hip_bf16.h>

// Problem constants
#define B_    64
#define S_    512
#define L_    256
#define D_    768      // K of GEMM1
#define RED_  400
#define REDP_ 512      // padded N of GEMM1 (storage stride) / K-stride of GEMM23
#define KEFF_ 416      // effective K of GEMM23 / effective N of GEMM1 (13 k-tiles)
#define HID_  100
#define HIDP_ 128      // padded N of GEMM23 / K of affine+triplet
#define TAGS_ 5
#define POL_  4
#define NBI_  512      // affine padded N (4 * 128)
#define NAO_  256      // fused ap|op GEMM N
#define BL_   (B_ * L_)  // 16384

typedef __attribute__((ext_vector_type(8))) short short8;
typedef __attribute__((ext_vector_type(4))) float f32x4;
typedef __attribute__((ext_vector_type(4))) unsigned short u16x4;

#define GLOAD_LDS16(gp, lp) __builtin_amdgcn_global_load_lds( \
    (const __attribute__((address_space(1))) void*)(gp),      \
    (__attribute__((address_space(3))) void*)(lp), 16, 0, 0)

__device__ inline float bf2f(unsigned short u) {
    union { unsigned int i; float f; } c; c.i = ((unsigned)u) << 16; return c.f;
}
__device__ inline unsigned short f2bf(float f) {
    __hip_bfloat16 h = __float2bfloat16(f);
    unsigned short u;
    __builtin_memcpy(&u, &h, 2);
    return u;
}

// ---------------------------------------------------------------------------
// 0+1) FRONT: blocks [0,4096) = segment mean; rest = weight/bias prep.
// ---------------------------------------------------------------------------
#define SZ0 393216
#define SZ1 131072
#define SZ2 65536
#define SZ3 512
#define SZ4 256
#define PREP_TOT (SZ0 + SZ1 + SZ2 + SZ3 + SZ4)
#define SEG_BLOCKS (BL_ / 4)
#define PREP_BLOCKS ((PREP_TOT + 255) / 256)

__global__ __launch_bounds__(256) void front_kernel(
    const float* __restrict__ bert, const int* __restrict__ pos,
    unsigned short* __restrict__ pooled,
    const float* __restrict__ W_reduc, const float* __restrict__ b_reduc,
    const float* __restrict__ W_ap, const float* __restrict__ b_ap,
    const float* __restrict__ W_op, const float* __restrict__ b_op,
    const float* __restrict__ W_bi,
    unsigned short* __restrict__ WtR, unsigned short* __restrict__ WtAO,
    unsigned short* __restrict__ WtBi,
    float* __restrict__ bR, float* __restrict__ bAO, float* __restrict__ bBi)
{
    if (blockIdx.x < SEG_BLOCKS) {
        int r  = threadIdx.x >> 6;
        int l  = threadIdx.x & 63;
        int bl = blockIdx.x * 4 + r;
        int b  = bl >> 8;
        int s  = pos[bl * 2 + 0];
        int e  = pos[bl * 2 + 1];
        int len = e - s + 1;                // 1 or 2
        const float* v0 = bert + ((size_t)b * S_ + s) * D_;
        float inv = (len == 2) ? 0.5f : 1.0f;
        unsigned short* outp = pooled + (size_t)bl * D_;
        #pragma unroll
        for (int c = 0; c < 3; ++c) {
            int d = l * 4 + c * 256;
            f32x4 x = *(const f32x4*)(v0 + d);
            if (len == 2) {
                f32x4 y = *(const f32x4*)(v0 + D_ + d);
                x += y;
            }
            u16x4 o;
            #pragma unroll
            for (int j = 0; j < 4; ++j) o[j] = f2bf(x[j] * inv);
            *(u16x4*)(outp + d) = o;
        }
        return;
    }

    int idx = (blockIdx.x - SEG_BLOCKS) * 256 + threadIdx.x;
    if (idx < SZ0) {
        int n = idx / D_, k = idx - n * D_;
        float v = (n < RED_) ? W_reduc[(size_t)k * RED_ + n] : 0.f;
        WtR[idx] = f2bf(v);
    } else if (idx < SZ0 + SZ1) {
        int i = idx - SZ0;
        int n = i >> 9, k = i & 511;
        float v = 0.f;
        if (k < RED_) {
            if (n < HID_)                      v = W_ap[(size_t)k * HID_ + n];
            else if (n >= 128 && n < 128+HID_) v = W_op[(size_t)k * HID_ + (n-128)];
        }
        WtAO[i] = f2bf(v);
    } else if (idx < SZ0 + SZ1 + SZ2) {
        int i = idx - SZ0 - SZ1;
        int n = i >> 7, k = i & 127;
        int p = n >> 7, h = n & 127;
        float v = (h < HID_ && k < HID_) ? W_bi[(size_t)k * RED_ + p * HID_ + h] : 0.f;
        WtBi[i] = f2bf(v);
        if (k == 0) bBi[n] = (h < HID_) ? W_bi[(size_t)HID_ * RED_ + p * HID_ + h] : 0.f;
    } else if (idx < SZ0 + SZ1 + SZ2 + SZ3) {
        int n = idx - SZ0 - SZ1 - SZ2;
        bR[n] = (n < RED_) ? b_reduc[n] : 0.f;
    } else if (idx < PREP_TOT) {
        int n = idx - SZ0 - SZ1 - SZ2 - SZ3;
        bAO[n] = (n < 128) ? ((n < HID_) ? b_ap[n] : 0.f)
                           : (((n-128) < HID_) ? b_op[n-128] : 0.f);
    }
}

// ---------------------------------------------------------------------------
// 2) GEMM1: h[:, 0:416] = relu(pooled @ WtR^T + bR), stride 512.
// nlim=416: fj frags with col >= 416 are skipped (never read downstream).
// ---------------------------------------------------------------------------
__global__ __launch_bounds__(256) void gemm1_kernel(
    const short* __restrict__ A, const short* __restrict__ Bt,
    const float* __restrict__ bias, unsigned short* __restrict__ Co,
    int M, int N, int K, int nlim)
{
    __shared__ __align__(16) short lds[2][8192];   // [buf][A 4096 | B 4096]

    const int t  = threadIdx.x;
    const int wv = t >> 6;
    const int ln = t & 63;
    const int wm = wv >> 1;
    const int wn = wv & 1;
    const int bm = blockIdx.x * 128;
    const int bn = blockIdx.y * 128;

    const int srow = t >> 2;
    const int skc  = (t & 3) * 8;

    int fjrem = (nlim - bn - wn * 64) >> 4;
    const int fjcnt = fjrem < 0 ? 0 : (fjrem > 4 ? 4 : fjrem);

    f32x4 acc[4][4] = {};
    const int NT = K >> 5;

    {
        #pragma unroll
        for (int q = 0; q < 2; ++q) {
            const short* g = A + (size_t)(bm + q * 64 + srow) * K + skc;
            GLOAD_LDS16(g, &lds[0][q * 2048 + wv * 512]);
        }
        #pragma unroll
        for (int q = 0; q < 2; ++q) {
            const short* g = Bt + (size_t)(bn + q * 64 + srow) * K + skc;
            GLOAD_LDS16(g, &lds[0][4096 + q * 2048 + wv * 512]);
        }
    }
    __syncthreads();

    int cur = 0;
    const int lr = ln & 15;
    const int lk = (ln >> 4) * 8;

    for (int kt = 0; kt < NT; ++kt) {
        if (kt + 1 < NT) {
            int k0 = (kt + 1) << 5;
            #pragma unroll
            for (int q = 0; q < 2; ++q) {
                const short* g = A + (size_t)(bm + q * 64 + srow) * K + k0 + skc;
                GLOAD_LDS16(g, &lds[cur ^ 1][q * 2048 + wv * 512]);
            }
            #pragma unroll
            for (int q = 0; q < 2; ++q) {
                const short* g = Bt + (size_t)(bn + q * 64 + srow) * K + k0 + skc;
                GLOAD_LDS16(g, &lds[cur ^ 1][4096 + q * 2048 + wv * 512]);
            }
        }

        const short* As = &lds[cur][0];
        const short* Bs = &lds[cur][4096];
        short8 a[4], b[4];
        #pragma unroll
        for (int fi = 0; fi < 4; ++fi)
            a[fi] = *(const short8*)(As + (wm * 64 + fi * 16 + lr) * 32 + lk);
        #pragma unroll
        for (int fj = 0; fj < 4; ++fj)
            if (fj < fjcnt)
                b[fj] = *(const short8*)(Bs + (wn * 64 + fj * 16 + lr) * 32 + lk);
        #pragma unroll
        for (int fi = 0; fi < 4; ++fi)
            #pragma unroll
            for (int fj = 0; fj < 4; ++fj)
                if (fj < fjcnt)
                    acc[fi][fj] = __builtin_amdgcn_mfma_f32_16x16x32_bf16(
                        a[fi], b[fj], acc[fi][fj], 0, 0, 0);

        __syncthreads();
        cur ^= 1;
    }

    const int row0 = bm + wm * 64 + (ln >> 4) * 4;
    const int col0 = bn + wn * 64 + lr;
    #pragma unroll
    for (int fi = 0; fi < 4; ++fi)
        #pragma unroll
        for (int r = 0; r < 4; ++r) {
            int row = row0 + fi * 16 + r;
            #pragma unroll
            for (int fj = 0; fj < 4; ++fj)
                if (fj < fjcnt) {
                    int col = col0 + fj * 16;
                    float v = fmaxf(acc[fi][fj][r] + bias[col], 0.f);
                    Co[(size_t)row * N + col] = f2bf(v);
                }
        }
}

// ---------------------------------------------------------------------------
// 3) GEMM23 + tag heads: [ap|op] = relu(h @ WtAO^T + bAO), split outputs.
// K-loop over 416 (13 tiles); row stride 512. Epilogue keeps the 128x128
// tile in LDS (fp32) and computes the 5-tag head for its rows.
// grid (128, 2): by=0 -> ap, by=1 -> op.
// ---------------------------------------------------------------------------
__global__ __launch_bounds__(256) void gemm23_tag_kernel(
    const short* __restrict__ A, const short* __restrict__ Bt,
    const float* __restrict__ bias,
    unsigned short* __restrict__ apOut, unsigned short* __restrict__ opOut,
    const float* __restrict__ Wap_tag, const float* __restrict__ bap_tag,
    const float* __restrict__ Wop_tag, const float* __restrict__ bop_tag,
    float* __restrict__ out_tag)
{
    __shared__ __align__(16) short lds[2][8192];
    __shared__ float tagf[128 * 101];
    __shared__ float Wtag[HID_ * TAGS_];
    __shared__ float Btag[TAGS_];

    const int t  = threadIdx.x;
    const int wv = t >> 6;
    const int ln = t & 63;
    const int wm = wv >> 1;
    const int wn = wv & 1;
    const int bm = blockIdx.x * 128;
    const int bn = blockIdx.y * 128;
    const int half = blockIdx.y;

    const float* Wt = half ? Wop_tag : Wap_tag;
    const float* bt = half ? bop_tag : bap_tag;
    for (int i = t; i < HID_ * TAGS_; i += 256) Wtag[i] = Wt[i];
    if (t < TAGS_) Btag[t] = bt[t];

    const int srow = t >> 2;
    const int skc  = (t & 3) * 8;
    const int NT = KEFF_ >> 5;   // 13

    f32x4 acc[4][4] = {};

    {
        #pragma unroll
        for (int q = 0; q < 2; ++q) {
            const short* g = A + (size_t)(bm + q * 64 + srow) * REDP_ + skc;
            GLOAD_LDS16(g, &lds[0][q * 2048 + wv * 512]);
        }
        #pragma unroll
        for (int q = 0; q < 2; ++q) {
            const short* g = Bt + (size_t)(bn + q * 64 + srow) * REDP_ + skc;
            GLOAD_LDS16(g, &lds[0][4096 + q * 2048 + wv * 512]);
        }
    }
    __syncthreads();

    int cur = 0;
    const int lr = ln & 15;
    const int lk = (ln >> 4) * 8;

    for (int kt = 0; kt < NT; ++kt) {
        if (kt + 1 < NT) {
            int k0 = (kt + 1) << 5;
            #pragma unroll
            for (int q = 0; q < 2; ++q) {
                const short* g = A + (size_t)(bm + q * 64 + srow) * REDP_ + k0 + skc;
                GLOAD_LDS16(g, &lds[cur ^ 1][q * 2048 + wv * 512]);
            }
            #pragma unroll
            for (int q = 0; q < 2; ++q) {
                const short* g = Bt + (size_t)(bn + q * 64 + srow) * REDP_ + k0 + skc;
                GLOAD_LDS16(g, &lds[cur ^ 1][4096 + q * 2048 + wv * 512]);
            }
        }

        const short* As = &lds[cur][0];
        const short* Bs = &lds[cur][4096];
        short8 a[4], b[4];
        #pragma unroll
        for (int fi = 0; fi < 4; ++fi)
            a[fi] = *(const short8*)(As + (wm * 64 + fi * 16 + lr) * 32 + lk);
        #pragma unroll
        for (int fj = 0; fj < 4; ++fj)
            b[fj] = *(const short8*)(Bs + (wn * 64 + fj * 16 + lr) * 32 + lk);
        #pragma unroll
        for (int fi = 0; fi < 4; ++fi)
            #pragma unroll
            for (int fj = 0; fj < 4; ++fj)
                acc[fi][fj] = __builtin_amdgcn_mfma_f32_16x16x32_bf16(
                    a[fi], b[fj], acc[fi][fj], 0, 0, 0);

        __syncthreads();
        cur ^= 1;
    }

    unsigned short* Co = half ? opOut : apOut;
    const int rl0 = wm * 64 + (ln >> 4) * 4;
    const int cl0 = wn * 64 + lr;
    #pragma unroll
    for (int fi = 0; fi < 4; ++fi)
        #pragma unroll
        for (int r = 0; r < 4; ++r) {
            int rl = rl0 + fi * 16 + r;
            #pragma unroll
            for (int fj = 0; fj < 4; ++fj) {
                int cl = cl0 + fj * 16;
                float v = fmaxf(acc[fi][fj][r] + bias[bn + cl], 0.f);
                Co[(size_t)(bm + rl) * 128 + cl] = f2bf(v);
                if (cl < 101) tagf[rl * 101 + cl] = v;
            }
        }
    __syncthreads();

    if (t < 128) {
        float s[TAGS_];
        #pragma unroll
        for (int g = 0; g < TAGS_; ++g) s[g] = Btag[g];
        const float* rowp = &tagf[t * 101];
        for (int k = 0; k < HID_; ++k) {
            float x = rowp[k];
            #pragma unroll
            for (int g = 0; g < TAGS_; ++g) s[g] += x * Wtag[k * TAGS_ + g];
        }
        float* o = out_tag + (size_t)half * (BL_ * TAGS_) + (size_t)(bm + t) * TAGS_;
        #pragma unroll
        for (int g = 0; g < TAGS_; ++g) o[g] = s[g];
    }
}

// ---------------------------------------------------------------------------
// 4) Affine (K=128, single-stage LDS): affine = ap @ WtBi^T + bBi -> bf16
//    grid (128, 4). LDS layout: 4 ks-subtiles of [128][32].
// ---------------------------------------------------------------------------
__global__ __launch_bounds__(256) void affine_kernel(
    const short* __restrict__ ap, const short* __restrict__ WtBi,
    const float* __restrict__ bBi, unsigned short* __restrict__ affine)
{
    __shared__ __align__(16) short As[16384];
    __shared__ __align__(16) short Bs[16384];

    const int t  = threadIdx.x;
    const int wv = t >> 6;
    const int ln = t & 63;
    const int wm = wv >> 1;
    const int wn = wv & 1;
    const int bm = blockIdx.x * 128;
    const int bn = blockIdx.y * 128;

    const int rsub = ln >> 2;       // 0..15
    const int j8   = (ln & 3) * 8;  // k chunk within 32

    #pragma unroll
    for (int i = 0; i < 8; ++i) {
        int ks = i >> 1, hf = i & 1;
        int rloc = wv * 32 + hf * 16;
        const short* gA = ap + (size_t)(bm + rloc + rsub) * HIDP_ + ks * 32 + j8;
        GLOAD_LDS16(gA, &As[ks * 4096 + rloc * 32]);
        const short* gB = WtBi + (size_t)(bn + rloc + rsub) * HIDP_ + ks * 32 + j8;
        GLOAD_LDS16(gB, &Bs[ks * 4096 + rloc * 32]);
    }
    __syncthreads();

    const int lr = ln & 15;
    const int lk = (ln >> 4) * 8;
    f32x4 acc[4][4] = {};

    #pragma unroll
    for (int ks = 0; ks < 4; ++ks) {
        short8 a[4], b[4];
        #pragma unroll
        for (int fi = 0; fi < 4; ++fi)
            a[fi] = *(const short8*)(As + ks * 4096 + (wm * 64 + fi * 16 + lr) * 32 + lk);
        #pragma unroll
        for (int fj = 0; fj < 4; ++fj)
            b[fj] = *(const short8*)(Bs + ks * 4096 + (wn * 64 + fj * 16 + lr) * 32 + lk);
        #pragma unroll
        for (int fi = 0; fi < 4; ++fi)
            #pragma unroll
            for (int fj = 0; fj < 4; ++fj)
                acc[fi][fj] = __builtin_amdgcn_mfma_f32_16x16x32_bf16(
                    a[fi], b[fj], acc[fi][fj], 0, 0, 0);
    }

    const int row0 = bm + wm * 64 + (ln >> 4) * 4;
    const int col0 = bn + wn * 64 + lr;
    #pragma unroll
    for (int fi = 0; fi < 4; ++fi)
        #pragma unroll
        for (int r = 0; r < 4; ++r) {
            int row = row0 + fi * 16 + r;
            #pragma unroll
            for (int fj = 0; fj < 4; ++fj) {
                int col = col0 + fj * 16;
                affine[(size_t)row * NBI_ + col] = f2bf(acc[fi][fj][r] + bBi[col]);
            }
        }
}

// ---------------------------------------------------------------------------
// 5) Triplet (K=128, single-stage LDS), SWAPPED operands:
//    D[ip, j] = sum_h aff[ip,h] * op[j,h]; lane's 4 acc regs = 4 consecutive
//    ip -> f32x4 stores to out[b, j, ip]. grid (2 j-tiles, 8 ip-tiles, 64).
// ---------------------------------------------------------------------------
__global__ __launch_bounds__(256) void triplet_kernel(
    const short* __restrict__ op, const short* __restrict__ affine,
    float* __restrict__ out)
{
    __shared__ __align__(16) short As[16384];   // op tile (j rows)
    __shared__ __align__(16) short Bs[16384];   // aff tile (ip rows)

    const int t  = threadIdx.x;
    const int wv = t >> 6;
    const int ln = t & 63;
    const int wm = wv >> 1;        // j half
    const int wn = wv & 1;         // ip half
    const int bm = blockIdx.x * 128;   // j base
    const int bn = blockIdx.y * 128;   // ip base
    const int b  = blockIdx.z;

    const short* Ab = op     + (size_t)b * 256 * HIDP_;
    const short* Bb = affine + (size_t)b * 256 * NBI_;

    const int rsub = ln >> 2;
    const int j8   = (ln & 3) * 8;

    #pragma unroll
    for (int i = 0; i < 8; ++i) {
        int ks = i >> 1, hf = i & 1;
        int rloc = wv * 32 + hf * 16;
        const short* gA = Ab + (size_t)(bm + rloc + rsub) * HIDP_ + ks * 32 + j8;
        GLOAD_LDS16(gA, &As[ks * 4096 + rloc * 32]);
        int ip = bn + rloc + rsub;
        const short* gB = Bb + (size_t)(ip >> 2) * NBI_ + (ip & 3) * HIDP_ + ks * 32 + j8;
        GLOAD_LDS16(gB, &Bs[ks * 4096 + rloc * 32]);
    }
    __syncthreads();

    const int lr = ln & 15;
    const int lk = (ln >> 4) * 8;
    f32x4 acc[4][4] = {};   // [fa: ip frag][fo: j frag]

    #pragma unroll
    for (int ks = 0; ks < 4; ++ks) {
        short8 af[4], of[4];
        #pragma unroll
        for (int fa = 0; fa < 4; ++fa)
            af[fa] = *(const short8*)(Bs + ks * 4096 + (wn * 64 + fa * 16 + lr) * 32 + lk);
        #pragma unroll
        for (int fo = 0; fo < 4; ++fo)
            of[fo] = *(const short8*)(As + ks * 4096 + (wm * 64 + fo * 16 + lr) * 32 + lk);
        #pragma unroll
        for (int fa = 0; fa < 4; ++fa)
            #pragma unroll
            for (int fo = 0; fo < 4; ++fo)
                acc[fa][fo] = __builtin_amdgcn_mfma_f32_16x16x32_bf16(
                    af[fa], of[fo], acc[fa][fo], 0, 0, 0);
    }

    // D rows = ip ((ln>>4)*4 + r), D cols = j (ln&15). 4 regs = 4 consec ip.
    float* O = out + (size_t)b * 256 * 1024;
    const int ipb = bn + wn * 64 + (ln >> 4) * 4;
    const int jb  = bm + wm * 64 + lr;
    #pragma unroll
    for (int fa = 0; fa < 4; ++fa) {
        int ip0 = ipb + fa * 16;
        #pragma unroll
        for (int fo = 0; fo < 4; ++fo) {
            int j = jb + fo * 16;
            *(f32x4*)(O + (size_t)j * 1024 + ip0) = acc[fa][fo];
        }
    }
}

// ---------------------------------------------------------------------------
extern "C" void kernel_launch(void* const* d_in, const int* in_sizes, int n_in,
                              void* d_out, int out_size, void* d_ws, size_t ws_size,
                              hipStream_t stream)
{
    const float* bert     = (const float*)d_in[0];
    const int*   pos      = (const int*)  d_in[1];
    const float* W_reduc  = (const float*)d_in[2];
    const float* b_reduc  = (const float*)d_in[3];
    const float* W_ap     = (const float*)d_in[4];
    const float* b_ap     = (const float*)d_in[5];
    const float* W_op     = (const float*)d_in[6];
    const float* b_op     = (const float*)d_in[7];
    const float* W_ap_tag = (const float*)d_in[8];
    const float* b_ap_tag = (const float*)d_in[9];
    const float* W_op_tag = (const float*)d_in[10];
    const float* b_op_tag = (const float*)d_in[11];
    const float* W_bi     = (const float*)d_in[12];

    float* out = (float*)d_out;

    // Workspace layout (bytes; all 16B-aligned)
    char* ws = (char*)d_ws;
    unsigned short* pooled = (unsigned short*)ws; ws += (size_t)BL_ * D_ * 2;
    unsigned short* h      = (unsigned short*)ws; ws += (size_t)BL_ * REDP_ * 2;
    unsigned short* ap     = (unsigned short*)ws; ws += (size_t)BL_ * HIDP_ * 2;
    unsigned short* opv    = (unsigned short*)ws; ws += (size_t)BL_ * HIDP_ * 2;
    unsigned short* affine = (unsigned short*)ws; ws += (size_t)BL_ * NBI_ * 2;
    unsigned short* WtR    = (unsigned short*)ws; ws += (size_t)REDP_ * D_ * 2;
    unsigned short* WtAO   = (unsigned short*)ws; ws += (size_t)NAO_ * REDP_ * 2;
    unsigned short* WtBi   = (unsigned short*)ws; ws += (size_t)NBI_ * HIDP_ * 2;
    float* bR  = (float*)ws;  ws += REDP_ * 4;
    float* bAO = (float*)ws;  ws += NAO_ * 4;
    float* bBi = (float*)ws;  ws += NBI_ * 4;

    // 0+1) seg_mean + prep (one launch)
    front_kernel<<<SEG_BLOCKS + PREP_BLOCKS, 256, 0, stream>>>(
        bert, pos, pooled,
        W_reduc, b_reduc, W_ap, b_ap, W_op, b_op, W_bi,
        WtR, WtAO, WtBi, bR, bAO, bBi);

    // 2) h[:, 0:416] = relu(pooled @ W_reduc + b), stride 512
    gemm1_kernel<<<dim3(BL_ / 128, REDP_ / 128), 256, 0, stream>>>(
        (const short*)pooled, (const short*)WtR, bR, h, BL_, REDP_, D_, KEFF_);

    // 3) ap|op = relu(h @ [W_ap|W_op] + b) + tag heads (K=416)
    gemm23_tag_kernel<<<dim3(BL_ / 128, 2), 256, 0, stream>>>(
        (const short*)h, (const short*)WtAO, bAO, ap, opv,
        W_ap_tag, b_ap_tag, W_op_tag, b_op_tag, out);

    // 4) affine = ap @ W_bi[:100] + W_bi[100]  [16384,128] x [512,128]^T
    affine_kernel<<<dim3(BL_ / 128, NBI_ / 128), 256, 0, stream>>>(
        (const short*)ap, (const short*)WtBi, bBi, affine);

    // 5) triplet -> out[163840 : ]
    triplet_kernel<<<dim3(2, 8, B_), 256, 0, stream>>>(
        (const short*)opv, (const short*)affine, out + 2 * BL_ * TAGS_);
}

// Round 9
// 82.714 us; speedup vs baseline: 1.1846x; 1.1846x over previous
//
#include <hip/hip_runtime.h>
#include <hip/hip_bf16.h>

// Problem constants
#define B_    64
#define S_    512
#define L_    256
#define D_    768      // K of GEMM1
#define RED_  400
#define REDP_ 512      // padded N of GEMM1 / K-stride of GEMM23
#define KEFF_ 416      // effective K of GEMM23 (13 k-tiles; h cols 400.. are 0)
#define HID_  100
#define HIDP_ 128      // padded N of GEMM23 / K of affine+triplet
#define TAGS_ 5
#define POL_  4
#define NBI_  512      // affine padded N (4 * 128)
#define NAO_  256      // fused ap|op GEMM N
#define BL_   (B_ * L_)  // 16384

typedef __attribute__((ext_vector_type(8))) short short8;
typedef __attribute__((ext_vector_type(4))) float f32x4;
typedef __attribute__((ext_vector_type(4))) unsigned short u16x4;

#define GLOAD_LDS16(gp, lp) __builtin_amdgcn_global_load_lds( \
    (const __attribute__((address_space(1))) void*)(gp),      \
    (__attribute__((address_space(3))) void*)(lp), 16, 0, 0)

__device__ inline float bf2f(unsigned short u) {
    union { unsigned int i; float f; } c; c.i = ((unsigned)u) << 16; return c.f;
}
__device__ inline unsigned short f2bf(float f) {
    __hip_bfloat16 h = __float2bfloat16(f);
    unsigned short u;
    __builtin_memcpy(&u, &h, 2);
    return u;
}

// ---------------------------------------------------------------------------
// 0+1) FRONT: blocks [0,4096) = segment mean; rest = weight/bias prep.
// ---------------------------------------------------------------------------
#define SZ0 393216
#define SZ1 131072
#define SZ2 65536
#define SZ3 512
#define SZ4 256
#define PREP_TOT (SZ0 + SZ1 + SZ2 + SZ3 + SZ4)
#define SEG_BLOCKS (BL_ / 4)
#define PREP_BLOCKS ((PREP_TOT + 255) / 256)

__global__ __launch_bounds__(256) void front_kernel(
    const float* __restrict__ bert, const int* __restrict__ pos,
    unsigned short* __restrict__ pooled,
    const float* __restrict__ W_reduc, const float* __restrict__ b_reduc,
    const float* __restrict__ W_ap, const float* __restrict__ b_ap,
    const float* __restrict__ W_op, const float* __restrict__ b_op,
    const float* __restrict__ W_bi,
    unsigned short* __restrict__ WtR, unsigned short* __restrict__ WtAO,
    unsigned short* __restrict__ WtBi,
    float* __restrict__ bR, float* __restrict__ bAO, float* __restrict__ bBi)
{
    if (blockIdx.x < SEG_BLOCKS) {
        int r  = threadIdx.x >> 6;
        int l  = threadIdx.x & 63;
        int bl = blockIdx.x * 4 + r;
        int b  = bl >> 8;
        int s  = pos[bl * 2 + 0];
        int e  = pos[bl * 2 + 1];
        int len = e - s + 1;                // 1 or 2
        const float* v0 = bert + ((size_t)b * S_ + s) * D_;
        float inv = (len == 2) ? 0.5f : 1.0f;
        unsigned short* outp = pooled + (size_t)bl * D_;
        #pragma unroll
        for (int c = 0; c < 3; ++c) {
            int d = l * 4 + c * 256;
            f32x4 x = *(const f32x4*)(v0 + d);
            if (len == 2) {
                f32x4 y = *(const f32x4*)(v0 + D_ + d);
                x += y;
            }
            u16x4 o;
            #pragma unroll
            for (int j = 0; j < 4; ++j) o[j] = f2bf(x[j] * inv);
            *(u16x4*)(outp + d) = o;
        }
        return;
    }

    int idx = (blockIdx.x - SEG_BLOCKS) * 256 + threadIdx.x;
    if (idx < SZ0) {
        int n = idx / D_, k = idx - n * D_;
        float v = (n < RED_) ? W_reduc[(size_t)k * RED_ + n] : 0.f;
        WtR[idx] = f2bf(v);
    } else if (idx < SZ0 + SZ1) {
        int i = idx - SZ0;
        int n = i >> 9, k = i & 511;
        float v = 0.f;
        if (k < RED_) {
            if (n < HID_)                      v = W_ap[(size_t)k * HID_ + n];
            else if (n >= 128 && n < 128+HID_) v = W_op[(size_t)k * HID_ + (n-128)];
        }
        WtAO[i] = f2bf(v);
    } else if (idx < SZ0 + SZ1 + SZ2) {
        int i = idx - SZ0 - SZ1;
        int n = i >> 7, k = i & 127;
        int p = n >> 7, h = n & 127;
        float v = (h < HID_ && k < HID_) ? W_bi[(size_t)k * RED_ + p * HID_ + h] : 0.f;
        WtBi[i] = f2bf(v);
        if (k == 0) bBi[n] = (h < HID_) ? W_bi[(size_t)HID_ * RED_ + p * HID_ + h] : 0.f;
    } else if (idx < SZ0 + SZ1 + SZ2 + SZ3) {
        int n = idx - SZ0 - SZ1 - SZ2;
        bR[n] = (n < RED_) ? b_reduc[n] : 0.f;
    } else if (idx < PREP_TOT) {
        int n = idx - SZ0 - SZ1 - SZ2 - SZ3;
        bAO[n] = (n < 128) ? ((n < HID_) ? b_ap[n] : 0.f)
                           : (((n-128) < HID_) ? b_op[n-128] : 0.f);
    }
}

// ---------------------------------------------------------------------------
// 2) GEMM1: h = relu(pooled[16384,768] @ WtR[512,768]^T + bR) -> bf16
// 128x128 tile, BK=32, 4 waves (2x2), double-buffered, global_load_lds x16.
// Unconditional (full N=512 write; cols 400.. are exact zeros).
// ---------------------------------------------------------------------------
__global__ __launch_bounds__(256) void gemm1_kernel(
    const short* __restrict__ A, const short* __restrict__ Bt,
    const float* __restrict__ bias, unsigned short* __restrict__ Co,
    int M, int N, int K)
{
    __shared__ __align__(16) short lds[2][8192];   // [buf][A 4096 | B 4096]

    const int t  = threadIdx.x;
    const int wv = t >> 6;
    const int ln = t & 63;
    const int wm = wv >> 1;
    const int wn = wv & 1;
    const int bm = blockIdx.x * 128;
    const int bn = blockIdx.y * 128;

    const int srow = t >> 2;
    const int skc  = (t & 3) * 8;

    f32x4 acc[4][4] = {};
    const int NT = K >> 5;

    {
        #pragma unroll
        for (int q = 0; q < 2; ++q) {
            const short* g = A + (size_t)(bm + q * 64 + srow) * K + skc;
            GLOAD_LDS16(g, &lds[0][q * 2048 + wv * 512]);
        }
        #pragma unroll
        for (int q = 0; q < 2; ++q) {
            const short* g = Bt + (size_t)(bn + q * 64 + srow) * K + skc;
            GLOAD_LDS16(g, &lds[0][4096 + q * 2048 + wv * 512]);
        }
    }
    __syncthreads();

    int cur = 0;
    const int lr = ln & 15;
    const int lk = (ln >> 4) * 8;

    for (int kt = 0; kt < NT; ++kt) {
        if (kt + 1 < NT) {
            int k0 = (kt + 1) << 5;
            #pragma unroll
            for (int q = 0; q < 2; ++q) {
                const short* g = A + (size_t)(bm + q * 64 + srow) * K + k0 + skc;
                GLOAD_LDS16(g, &lds[cur ^ 1][q * 2048 + wv * 512]);
            }
            #pragma unroll
            for (int q = 0; q < 2; ++q) {
                const short* g = Bt + (size_t)(bn + q * 64 + srow) * K + k0 + skc;
                GLOAD_LDS16(g, &lds[cur ^ 1][4096 + q * 2048 + wv * 512]);
            }
        }

        const short* As = &lds[cur][0];
        const short* Bs = &lds[cur][4096];
        short8 a[4], b[4];
        #pragma unroll
        for (int fi = 0; fi < 4; ++fi)
            a[fi] = *(const short8*)(As + (wm * 64 + fi * 16 + lr) * 32 + lk);
        #pragma unroll
        for (int fj = 0; fj < 4; ++fj)
            b[fj] = *(const short8*)(Bs + (wn * 64 + fj * 16 + lr) * 32 + lk);
        #pragma unroll
        for (int fi = 0; fi < 4; ++fi)
            #pragma unroll
            for (int fj = 0; fj < 4; ++fj)
                acc[fi][fj] = __builtin_amdgcn_mfma_f32_16x16x32_bf16(
                    a[fi], b[fj], acc[fi][fj], 0, 0, 0);

        __syncthreads();
        cur ^= 1;
    }

    const int row0 = bm + wm * 64 + (ln >> 4) * 4;
    const int col0 = bn + wn * 64 + lr;
    #pragma unroll
    for (int fi = 0; fi < 4; ++fi)
        #pragma unroll
        for (int r = 0; r < 4; ++r) {
            int row = row0 + fi * 16 + r;
            #pragma unroll
            for (int fj = 0; fj < 4; ++fj) {
                int col = col0 + fj * 16;
                float v = fmaxf(acc[fi][fj][r] + bias[col], 0.f);
                Co[(size_t)row * N + col] = f2bf(v);
            }
        }
}

// ---------------------------------------------------------------------------
// 3) GEMM23 + tag heads: [ap|op] = relu(h @ WtAO^T + bAO), split outputs.
// K-loop over 416 (13 tiles, compile-time); row stride 512. Epilogue keeps
// the 128x128 tile in LDS (fp32) and computes the 5-tag head for its rows.
// grid (128, 2): by=0 -> ap, by=1 -> op.
// ---------------------------------------------------------------------------
__global__ __launch_bounds__(256) void gemm23_tag_kernel(
    const short* __restrict__ A, const short* __restrict__ Bt,
    const float* __restrict__ bias,
    unsigned short* __restrict__ apOut, unsigned short* __restrict__ opOut,
    const float* __restrict__ Wap_tag, const float* __restrict__ bap_tag,
    const float* __restrict__ Wop_tag, const float* __restrict__ bop_tag,
    float* __restrict__ out_tag)
{
    __shared__ __align__(16) short lds[2][8192];
    __shared__ float tagf[128 * 101];
    __shared__ float Wtag[HID_ * TAGS_];
    __shared__ float Btag[TAGS_];

    const int t  = threadIdx.x;
    const int wv = t >> 6;
    const int ln = t & 63;
    const int wm = wv >> 1;
    const int wn = wv & 1;
    const int bm = blockIdx.x * 128;
    const int bn = blockIdx.y * 128;
    const int half = blockIdx.y;

    const float* Wt = half ? Wop_tag : Wap_tag;
    const float* bt = half ? bop_tag : bap_tag;
    for (int i = t; i < HID_ * TAGS_; i += 256) Wtag[i] = Wt[i];
    if (t < TAGS_) Btag[t] = bt[t];

    const int srow = t >> 2;
    const int skc  = (t & 3) * 8;
    const int NT = KEFF_ >> 5;   // 13 (compile-time)

    f32x4 acc[4][4] = {};

    {
        #pragma unroll
        for (int q = 0; q < 2; ++q) {
            const short* g = A + (size_t)(bm + q * 64 + srow) * REDP_ + skc;
            GLOAD_LDS16(g, &lds[0][q * 2048 + wv * 512]);
        }
        #pragma unroll
        for (int q = 0; q < 2; ++q) {
            const short* g = Bt + (size_t)(bn + q * 64 + srow) * REDP_ + skc;
            GLOAD_LDS16(g, &lds[0][4096 + q * 2048 + wv * 512]);
        }
    }
    __syncthreads();

    int cur = 0;
    const int lr = ln & 15;
    const int lk = (ln >> 4) * 8;

    for (int kt = 0; kt < NT; ++kt) {
        if (kt + 1 < NT) {
            int k0 = (kt + 1) << 5;
            #pragma unroll
            for (int q = 0; q < 2; ++q) {
                const short* g = A + (size_t)(bm + q * 64 + srow) * REDP_ + k0 + skc;
                GLOAD_LDS16(g, &lds[cur ^ 1][q * 2048 + wv * 512]);
            }
            #pragma unroll
            for (int q = 0; q < 2; ++q) {
                const short* g = Bt + (size_t)(bn + q * 64 + srow) * REDP_ + k0 + skc;
                GLOAD_LDS16(g, &lds[cur ^ 1][4096 + q * 2048 + wv * 512]);
            }
        }

        const short* As = &lds[cur][0];
        const short* Bs = &lds[cur][4096];
        short8 a[4], b[4];
        #pragma unroll
        for (int fi = 0; fi < 4; ++fi)
            a[fi] = *(const short8*)(As + (wm * 64 + fi * 16 + lr) * 32 + lk);
        #pragma unroll
        for (int fj = 0; fj < 4; ++fj)
            b[fj] = *(const short8*)(Bs + (wn * 64 + fj * 16 + lr) * 32 + lk);
        #pragma unroll
        for (int fi = 0; fi < 4; ++fi)
            #pragma unroll
            for (int fj = 0; fj < 4; ++fj)
                acc[fi][fj] = __builtin_amdgcn_mfma_f32_16x16x32_bf16(
                    a[fi], b[fj], acc[fi][fj], 0, 0, 0);

        __syncthreads();
        cur ^= 1;
    }

    unsigned short* Co = half ? opOut : apOut;
    const int rl0 = wm * 64 + (ln >> 4) * 4;
    const int cl0 = wn * 64 + lr;
    #pragma unroll
    for (int fi = 0; fi < 4; ++fi)
        #pragma unroll
        for (int r = 0; r < 4; ++r) {
            int rl = rl0 + fi * 16 + r;
            #pragma unroll
            for (int fj = 0; fj < 4; ++fj) {
                int cl = cl0 + fj * 16;
                float v = fmaxf(acc[fi][fj][r] + bias[bn + cl], 0.f);
                Co[(size_t)(bm + rl) * 128 + cl] = f2bf(v);
                if (cl < 101) tagf[rl * 101 + cl] = v;
            }
        }
    __syncthreads();

    if (t < 128) {
        float s[TAGS_];
        #pragma unroll
        for (int g = 0; g < TAGS_; ++g) s[g] = Btag[g];
        const float* rowp = &tagf[t * 101];
        for (int k = 0; k < HID_; ++k) {
            float x = rowp[k];
            #pragma unroll
            for (int g = 0; g < TAGS_; ++g) s[g] += x * Wtag[k * TAGS_ + g];
        }
        float* o = out_tag + (size_t)half * (BL_ * TAGS_) + (size_t)(bm + t) * TAGS_;
        #pragma unroll
        for (int g = 0; g < TAGS_; ++g) o[g] = s[g];
    }
}

// ---------------------------------------------------------------------------
// 4) Affine (K=128, single-stage LDS): affine = ap @ WtBi^T + bBi -> bf16
//    grid (128, 4). LDS layout: 4 ks-subtiles of [128][32].
// ---------------------------------------------------------------------------
__global__ __launch_bounds__(256) void affine_kernel(
    const short* __restrict__ ap, const short* __restrict__ WtBi,
    const float* __restrict__ bBi, unsigned short* __restrict__ affine)
{
    __shared__ __align__(16) short As[16384];
    __shared__ __align__(16) short Bs[16384];

    const int t  = threadIdx.x;
    const int wv = t >> 6;
    const int ln = t & 63;
    const int wm = wv >> 1;
    const int wn = wv & 1;
    const int bm = blockIdx.x * 128;
    const int bn = blockIdx.y * 128;

    const int rsub = ln >> 2;       // 0..15
    const int j8   = (ln & 3) * 8;  // k chunk within 32

    #pragma unroll
    for (int i = 0; i < 8; ++i) {
        int ks = i >> 1, hf = i & 1;
        int rloc = wv * 32 + hf * 16;
        const short* gA = ap + (size_t)(bm + rloc + rsub) * HIDP_ + ks * 32 + j8;
        GLOAD_LDS16(gA, &As[ks * 4096 + rloc * 32]);
        const short* gB = WtBi + (size_t)(bn + rloc + rsub) * HIDP_ + ks * 32 + j8;
        GLOAD_LDS16(gB, &Bs[ks * 4096 + rloc * 32]);
    }
    __syncthreads();

    const int lr = ln & 15;
    const int lk = (ln >> 4) * 8;
    f32x4 acc[4][4] = {};

    #pragma unroll
    for (int ks = 0; ks < 4; ++ks) {
        short8 a[4], b[4];
        #pragma unroll
        for (int fi = 0; fi < 4; ++fi)
            a[fi] = *(const short8*)(As + ks * 4096 + (wm * 64 + fi * 16 + lr) * 32 + lk);
        #pragma unroll
        for (int fj = 0; fj < 4; ++fj)
            b[fj] = *(const short8*)(Bs + ks * 4096 + (wn * 64 + fj * 16 + lr) * 32 + lk);
        #pragma unroll
        for (int fi = 0; fi < 4; ++fi)
            #pragma unroll
            for (int fj = 0; fj < 4; ++fj)
                acc[fi][fj] = __builtin_amdgcn_mfma_f32_16x16x32_bf16(
                    a[fi], b[fj], acc[fi][fj], 0, 0, 0);
    }

    const int row0 = bm + wm * 64 + (ln >> 4) * 4;
    const int col0 = bn + wn * 64 + lr;
    #pragma unroll
    for (int fi = 0; fi < 4; ++fi)
        #pragma unroll
        for (int r = 0; r < 4; ++r) {
            int row = row0 + fi * 16 + r;
            #pragma unroll
            for (int fj = 0; fj < 4; ++fj) {
                int col = col0 + fj * 16;
                affine[(size_t)row * NBI_ + col] = f2bf(acc[fi][fj][r] + bBi[col]);
            }
        }
}

// ---------------------------------------------------------------------------
// 5) Triplet (K=128, single-stage LDS): per batch b,
//    C[j, ip] = sum_h op[b,j,h] * affine[b, ip>>2, (ip&3)*128 + h] -> fp32.
//    grid (2, 8, 64).
// ---------------------------------------------------------------------------
__global__ __launch_bounds__(256) void triplet_kernel(
    const short* __restrict__ op, const short* __restrict__ affine,
    float* __restrict__ out)
{
    __shared__ __align__(16) short As[16384];
    __shared__ __align__(16) short Bs[16384];

    const int t  = threadIdx.x;
    const int wv = t >> 6;
    const int ln = t & 63;
    const int wm = wv >> 1;
    const int wn = wv & 1;
    const int bm = blockIdx.x * 128;
    const int bn = blockIdx.y * 128;
    const int b  = blockIdx.z;

    const short* Ab = op     + (size_t)b * 256 * HIDP_;
    const short* Bb = affine + (size_t)b * 256 * NBI_;

    const int rsub = ln >> 2;
    const int j8   = (ln & 3) * 8;

    #pragma unroll
    for (int i = 0; i < 8; ++i) {
        int ks = i >> 1, hf = i & 1;
        int rloc = wv * 32 + hf * 16;
        const short* gA = Ab + (size_t)(bm + rloc + rsub) * HIDP_ + ks * 32 + j8;
        GLOAD_LDS16(gA, &As[ks * 4096 + rloc * 32]);
        int ip = bn + rloc + rsub;
        const short* gB = Bb + (size_t)(ip >> 2) * NBI_ + (ip & 3) * HIDP_ + ks * 32 + j8;
        GLOAD_LDS16(gB, &Bs[ks * 4096 + rloc * 32]);
    }
    __syncthreads();

    const int lr = ln & 15;
    const int lk = (ln >> 4) * 8;
    f32x4 acc[4][4] = {};

    #pragma unroll
    for (int ks = 0; ks < 4; ++ks) {
        short8 a[4], bf[4];
        #pragma unroll
        for (int fi = 0; fi < 4; ++fi)
            a[fi] = *(const short8*)(As + ks * 4096 + (wm * 64 + fi * 16 + lr) * 32 + lk);
        #pragma unroll
        for (int fj = 0; fj < 4; ++fj)
            bf[fj] = *(const short8*)(Bs + ks * 4096 + (wn * 64 + fj * 16 + lr) * 32 + lk);
        #pragma unroll
        for (int fi = 0; fi < 4; ++fi)
            #pragma unroll
            for (int fj = 0; fj < 4; ++fj)
                acc[fi][fj] = __builtin_amdgcn_mfma_f32_16x16x32_bf16(
                    a[fi], bf[fj], acc[fi][fj], 0, 0, 0);
    }

    float* O = out + (size_t)b * 256 * 1024;
    const int row0 = bm + wm * 64 + (ln >> 4) * 4;
    const int col0 = bn + wn * 64 + lr;
    #pragma unroll
    for (int fi = 0; fi < 4; ++fi)
        #pragma unroll
        for (int r = 0; r < 4; ++r) {
            int row = row0 + fi * 16 + r;
            #pragma unroll
            for (int fj = 0; fj < 4; ++fj)
                O[(size_t)row * 1024 + col0 + fj * 16] = acc[fi][fj][r];
        }
}

// ---------------------------------------------------------------------------
extern "C" void kernel_launch(void* const* d_in, const int* in_sizes, int n_in,
                              void* d_out, int out_size, void* d_ws, size_t ws_size,
                              hipStream_t stream)
{
    const float* bert     = (const float*)d_in[0];
    const int*   pos      = (const int*)  d_in[1];
    const float* W_reduc  = (const float*)d_in[2];
    const float* b_reduc  = (const float*)d_in[3];
    const float* W_ap     = (const float*)d_in[4];
    const float* b_ap     = (const float*)d_in[5];
    const float* W_op     = (const float*)d_in[6];
    const float* b_op     = (const float*)d_in[7];
    const float* W_ap_tag = (const float*)d_in[8];
    const float* b_ap_tag = (const float*)d_in[9];
    const float* W_op_tag = (const float*)d_in[10];
    const float* b_op_tag = (const float*)d_in[11];
    const float* W_bi     = (const float*)d_in[12];

    float* out = (float*)d_out;

    // Workspace layout (bytes; all 16B-aligned)
    char* ws = (char*)d_ws;
    unsigned short* pooled = (unsigned short*)ws; ws += (size_t)BL_ * D_ * 2;
    unsigned short* h      = (unsigned short*)ws; ws += (size_t)BL_ * REDP_ * 2;
    unsigned short* ap     = (unsigned short*)ws; ws += (size_t)BL_ * HIDP_ * 2;
    unsigned short* opv    = (unsigned short*)ws; ws += (size_t)BL_ * HIDP_ * 2;
    unsigned short* affine = (unsigned short*)ws; ws += (size_t)BL_ * NBI_ * 2;
    unsigned short* WtR    = (unsigned short*)ws; ws += (size_t)REDP_ * D_ * 2;
    unsigned short* WtAO   = (unsigned short*)ws; ws += (size_t)NAO_ * REDP_ * 2;
    unsigned short* WtBi   = (unsigned short*)ws; ws += (size_t)NBI_ * HIDP_ * 2;
    float* bR  = (float*)ws;  ws += REDP_ * 4;
    float* bAO = (float*)ws;  ws += NAO_ * 4;
    float* bBi = (float*)ws;  ws += NBI_ * 4;

    // 0+1) seg_mean + prep (one launch)
    front_kernel<<<SEG_BLOCKS + PREP_BLOCKS, 256, 0, stream>>>(
        bert, pos, pooled,
        W_reduc, b_reduc, W_ap, b_ap, W_op, b_op, W_bi,
        WtR, WtAO, WtBi, bR, bAO, bBi);

    // 2) h = relu(pooled @ W_reduc + b)  [16384,768] x [512,768]^T (full N)
    gemm1_kernel<<<dim3(BL_ / 128, REDP_ / 128), 256, 0, stream>>>(
        (const short*)pooled, (const short*)WtR, bR, h, BL_, REDP_, D_);

    // 3) ap|op = relu(h @ [W_ap|W_op] + b) + tag heads (K=416, 13 tiles)
    gemm23_tag_kernel<<<dim3(BL_ / 128, 2), 256, 0, stream>>>(
        (const short*)h, (const short*)WtAO, bAO, ap, opv,
        W_ap_tag, b_ap_tag, W_op_tag, b_op_tag, out);

    // 4) affine = ap @ W_bi[:100] + W_bi[100]  [16384,128] x [512,128]^T
    affine_kernel<<<dim3(BL_ / 128, NBI_ / 128), 256, 0, stream>>>(
        (const short*)ap, (const short*)WtBi, bBi, affine);

    // 5) triplet -> out[163840 : ]
    triplet_kernel<<<dim3(2, 8, B_), 256, 0, stream>>>(
        (const short*)opv, (const short*)affine, out + 2 * BL_ * TAGS_);
}